// Round 5
// baseline (819.950 us; speedup 1.0000x reference)
//
#include <hip/hip_runtime.h>

#define TT 256
#define OBS 96
#define ACTD 32
#define RPB 8      // batch rows per block; grid = 256 -> 1 block/CU
#define CH 8       // steps per octave
#define XCS 136    // xchunk row stride (u16); 272B row -> 16B-aligned b128 frag reads
#define ZXS 12     // zxT per-col u16 (8 valid rows + pad); 24B col stride (8B-aligned uint2)
#define ZBS 69     // zbuf col stride (f32), odd -> spread banks
#define HBS 72     // hh row stride (u16); 144B row -> 16B-aligned b128 frag reads
#define EPS 1e-12f

typedef _Float16 f16x8 __attribute__((ext_vector_type(8)));
typedef float f32x4 __attribute__((ext_vector_type(4)));
typedef unsigned short u16x8 __attribute__((ext_vector_type(8)));
typedef unsigned int u32;
typedef unsigned short u16;

__device__ __forceinline__ u16 f2h(float f) {            // fp32 -> fp16 RNE
  return __builtin_bit_cast(u16, (_Float16)f);
}
__device__ __forceinline__ u32 pk2h(float a, float b) {
  return (u32)f2h(a) | ((u32)f2h(b) << 16);
}
__device__ __forceinline__ float h2f_lo(u32 v) {
  return (float)__builtin_bit_cast(_Float16, (u16)(v & 0xffffu));
}
__device__ __forceinline__ float h2f_hi(u32 v) {
  return (float)__builtin_bit_cast(_Float16, (u16)(v >> 16));
}
__device__ __forceinline__ float sigm(float x) { return 1.0f / (1.0f + __expf(-x)); }
__device__ __forceinline__ float tanh_(float x) { return 1.0f - 2.0f / (__expf(2.0f * x) + 1.0f); }

template <int CTRL>
__device__ __forceinline__ float dpp_add(float x) {
  int t = __builtin_amdgcn_update_dpp(0, __builtin_bit_cast(int, x), CTRL, 0xF, 0xF, true);
  return x + __builtin_bit_cast(float, t);
}
__device__ __forceinline__ float red16(float x) {   // sum within 16-lane groups, pure VALU
  x = dpp_add<0xB1>(x);   // quad_perm xor1
  x = dpp_add<0x4E>(x);   // quad_perm xor2
  x = dpp_add<0x124>(x);  // row_ror:4
  x = dpp_add<0x128>(x);  // row_ror:8
  return x;
}
__device__ __forceinline__ float red64(float x) {   // full-wave sum (r0-proven)
  x = red16(x);
  x += __shfl_xor(x, 16, 64);
  x += __shfl_xor(x, 32, 64);
  return x;
}

// LDS-only barrier (r4-proven correct): raw s_barrier + lgkmcnt(0), no vmcnt
// drain -> producer global loads / q stores stay in flight across barriers.
__device__ __forceinline__ void barrier_lds() {
  __builtin_amdgcn_sched_barrier(0);
  asm volatile("s_waitcnt lgkmcnt(0)" ::: "memory");
  __builtin_amdgcn_s_barrier();
  __builtin_amdgcn_sched_barrier(0);
}

// Wave-specialized LSTM: 8 rows x 256 steps, 512 thr, 1 block/CU.
// CONSUMERS (waves 0-3): wave g owns gate g (64 cols) -> gate LN sums complete
//   in-wave (red16 only, no cross-wave combine). Phase 2: rows {g, g+4}, col=ln.
// PRODUCERS (waves 4-7): wave owns cols [64(w-4), +64). Per octave o they build
//   z_x for octave o+1 (one col-tile per step, W frags reloaded from L2 each
//   step -> no persistent x-part W registers), stream-stage x(o+2), and compute
//   q for octave o-1 -- all off the recurrence chain, filling consumer stalls
//   on the shared SIMD. Double-buffered zxT/xchunk/hh by octave parity.
__global__ __launch_bounds__(512, 2) void lstm_fused(
    const float* __restrict__ obss, const float* __restrict__ actions,
    const float* __restrict__ Wm, const float* __restrict__ gamma,
    const float* __restrict__ beta, const float* __restrict__ dWv,
    const float* __restrict__ dbv, float* __restrict__ out)
{
  __shared__ u16 xchunk[2][CH][RPB][XCS];   // fp16 x, double-buffered   (34816 B)
  __shared__ u16 zxT[2][CH][256][ZXS];      // fp16 z_x^T, dbuf          (98304 B)
  __shared__ float zbuf[4][RPB][ZBS];       // z per [gate][row][col]    (8832 B)
  __shared__ float pbuf[4][RPB][2];         // gate-LN sums (s, ss)      (256 B)
  __shared__ u16 hh[2][CH][RPB][HBS];       // fp16 h history, dbuf      (18432 B)

  const int tid = threadIdx.x;
  const int wv = tid >> 6;
  const int ln = tid & 63;
  const int l15 = ln & 15;
  const int quad = ln >> 4;
  const int g = wv & 3;                     // consumer gate / producer col-span
  const bool cons = wv < 4;
  const int n0 = blockIdx.x * RPB;

  for (int i = tid; i < 2 * CH * RPB * HBS / 2; i += 512) ((u32*)hh)[i] = 0u;

  // stager mapping (all threads in prologue; producers reuse in-loop)
  const int oct01 = tid >> 8;               // 0: stage octave 0, 1: octave 1
  const int srow = (tid >> 5) & 7;
  const int slot = tid & 31;                // <24: obs float4, else action float4
  const float* obs_p = obss + (size_t)(n0 + srow) * TT * OBS;
  const float* act_p = actions + (size_t)(n0 + srow) * TT * ACTD;

  // prologue: stage x(oct0) -> xchunk[0], x(oct1) -> xchunk[1]
  #pragma unroll
  for (int s = 0; s < CH; ++s) {
    const int tl = oct01 * 8 + s;
    const f32x4 v = (slot < 24) ? *(const f32x4*)(obs_p + tl * OBS + slot * 4)
                                : *(const f32x4*)(act_p + tl * ACTD + (slot - 24) * 4);
    *(uint2*)&xchunk[oct01][s][srow][slot * 4] =
        make_uint2(pk2h(v[0], v[1]), pk2h(v[2], v[3]));
  }

  // consumer-persistent W h-part fragments: k = 128 + kt*32 + quad*8 + j
  u16x8 bwh[2][4];
  float ggam[4], gbet[4];
  float cgam = 0.f, cbet = 0.f;
  if (cons) {
    #pragma unroll
    for (int kt = 0; kt < 2; ++kt)
      #pragma unroll
      for (int ct = 0; ct < 4; ++ct)
        #pragma unroll
        for (int j = 0; j < 8; ++j)
          bwh[kt][ct][j] =
              f2h(Wm[(128 + kt * 32 + quad * 8 + j) * 256 + g * 64 + ct * 16 + l15]);
    #pragma unroll
    for (int gg = 0; gg < 4; ++gg) {
      ggam[gg] = gamma[gg * 64 + ln];
      gbet[gg] = beta[gg * 64 + ln];
    }
    cgam = gamma[4 * 64 + ln]; cbet = beta[4 * 64 + ln];
  }
  const float dw = dWv[ln];
  const float bias = dbv[0];

  __syncthreads();

  // prologue: producers fill zxT[0] from xchunk[0]
  if (!cons) {
    #pragma unroll
    for (int ct = 0; ct < 4; ++ct) {
      const int col = g * 64 + ct * 16 + l15;
      u16x8 fr[4];
      #pragma unroll
      for (int kt = 0; kt < 4; ++kt)
        #pragma unroll
        for (int j = 0; j < 8; ++j)
          fr[kt][j] = f2h(Wm[(kt * 32 + quad * 8 + j) * 256 + col]);
      #pragma unroll
      for (int s = 0; s < CH; ++s) {
        f32x4 ax = {0.f, 0.f, 0.f, 0.f};
        #pragma unroll
        for (int kt = 0; kt < 4; ++kt) {
          const u16x8 afx = *(const u16x8*)&xchunk[0][s][l15 & 7][kt * 32 + quad * 8];
          ax = __builtin_amdgcn_mfma_f32_16x16x32_f16(
              __builtin_bit_cast(f16x8, afx), __builtin_bit_cast(f16x8, fr[kt]), ax, 0, 0, 0);
        }
        if (quad < 2)
          *(uint2*)&zxT[0][s][col][quad * 4] =
              make_uint2(pk2h(ax[0], ax[1]), pk2h(ax[2], ax[3]));
      }
    }
  }
  __syncthreads();

  float creg0 = 0.f, creg1 = 0.f;           // c for rows g, g+4 (consumers)

  for (int t = 0; t < TT; ++t) {
    const int tm = t & 7;
    const int o = t >> 3;
    const int buf = o & 1, nb = buf ^ 1;

    if (cons) {
      // ---- phase 1: z = h.Wh + z_x for gate g, then in-wave gate LN sums ----
      const int rb = (tm == 0) ? nb : buf;   // hh buffer holding h(t-1)
      const int tp = (tm == 0) ? 7 : tm - 1;
      const u16x8 afh0 = *(const u16x8*)&hh[rb][tp][l15 & 7][quad * 8];
      const u16x8 afh1 = *(const u16x8*)&hh[rb][tp][l15 & 7][32 + quad * 8];
      f32x4 acc[4];
      #pragma unroll
      for (int ct = 0; ct < 4; ++ct) {
        f32x4 a = {0.f, 0.f, 0.f, 0.f};
        a = __builtin_amdgcn_mfma_f32_16x16x32_f16(
            __builtin_bit_cast(f16x8, afh0), __builtin_bit_cast(f16x8, bwh[0][ct]), a, 0, 0, 0);
        a = __builtin_amdgcn_mfma_f32_16x16x32_f16(
            __builtin_bit_cast(f16x8, afh1), __builtin_bit_cast(f16x8, bwh[1][ct]), a, 0, 0, 0);
        const uint2 zx = *(const uint2*)&zxT[buf][tm][g * 64 + ct * 16 + l15][(quad & 1) * 4];
        a[0] += h2f_lo(zx.x); a[1] += h2f_hi(zx.x);
        a[2] += h2f_lo(zx.y); a[3] += h2f_hi(zx.y);
        acc[ct] = a;
      }
      if (quad < 2) {                        // valid batch rows 0..7
        #pragma unroll
        for (int ct = 0; ct < 4; ++ct)
          #pragma unroll
          for (int r = 0; r < 4; ++r)
            zbuf[g][quad * 4 + r][ct * 16 + l15] = acc[ct][r];
      }
      float s[4], ss[4];
      #pragma unroll
      for (int r = 0; r < 4; ++r) {
        s[r]  = red16((acc[0][r] + acc[1][r]) + (acc[2][r] + acc[3][r]));
        ss[r] = red16((acc[0][r] * acc[0][r] + acc[1][r] * acc[1][r]) +
                      (acc[2][r] * acc[2][r] + acc[3][r] * acc[3][r]));
      }
      if (quad < 2 && l15 < 4) {
        const float sv  = l15 == 0 ? s[0]  : l15 == 1 ? s[1]  : l15 == 2 ? s[2]  : s[3];
        const float ssv = l15 == 0 ? ss[0] : l15 == 1 ? ss[1] : l15 == 2 ? ss[2] : ss[3];
        *(float2*)&pbuf[g][quad * 4 + l15][0] = make_float2(sv, ssv);
      }
    } else {
      // ---- producer A: z_x(o+1) col-tile ct=tm (steps 0..3) ----
      if (tm < 4 && t < TT - 8) {
        const int ct = tm;
        const int col = g * 64 + ct * 16 + l15;
        u16x8 fr[4];
        #pragma unroll
        for (int kt = 0; kt < 4; ++kt)
          #pragma unroll
          for (int j = 0; j < 8; ++j)
            fr[kt][j] = f2h(Wm[(kt * 32 + quad * 8 + j) * 256 + col]);
        #pragma unroll
        for (int s = 0; s < CH; ++s) {
          f32x4 ax = {0.f, 0.f, 0.f, 0.f};
          #pragma unroll
          for (int kt = 0; kt < 4; ++kt) {
            const u16x8 afx = *(const u16x8*)&xchunk[nb][s][l15 & 7][kt * 32 + quad * 8];
            ax = __builtin_amdgcn_mfma_f32_16x16x32_f16(
                __builtin_bit_cast(f16x8, afx), __builtin_bit_cast(f16x8, fr[kt]), ax, 0, 0, 0);
          }
          if (quad < 2)
            *(uint2*)&zxT[nb][s][col][quad * 4] =
                make_uint2(pk2h(ax[0], ax[1]), pk2h(ax[2], ax[3]));
        }
      }
      // ---- producer: q for step t-8 (octave o-1, slice tm), rows 2pw, 2pw+1 ----
      if (t >= 8) {
        const int ra = 2 * (wv - 4);
        const float hv0 = (float)__builtin_bit_cast(_Float16, hh[nb][tm][ra][ln]);
        const float hv1 = (float)__builtin_bit_cast(_Float16, hh[nb][tm][ra + 1][ln]);
        const float q0 = red64(hv0 * dw);
        const float q1 = red64(hv1 * dw);
        if (ln == 0) {
          out[(size_t)(n0 + ra) * TT + (t - 8)] = q0 + bias;
          out[(size_t)(n0 + ra + 1) * TT + (t - 8)] = q1 + bias;
        }
      }
    }
    barrier_lds();

    if (cons) {
      // ---- phase 2: rows g and g+4, col = ln ----
      float zc0[4], zc1[4];
      #pragma unroll
      for (int gg = 0; gg < 4; ++gg) {
        const float2 pa = *(const float2*)&pbuf[gg][g][0];
        const float2 pb = *(const float2*)&pbuf[gg][g + 4][0];
        const float m0 = pa.x * (1.0f / 64.0f);
        const float v0 = pa.y * (1.0f / 64.0f) - m0 * m0;
        const float m1 = pb.x * (1.0f / 64.0f);
        const float v1 = pb.y * (1.0f / 64.0f) - m1 * m1;
        zc0[gg] = (zbuf[gg][g][ln] - m0) * rsqrtf(v0 + EPS) * ggam[gg] + gbet[gg];
        zc1[gg] = (zbuf[gg][g + 4][ln] - m1) * rsqrtf(v1 + EPS) * ggam[gg] + gbet[gg];
      }
      const float nc0 = creg0 * sigm(zc0[2] + 1.0f) + sigm(zc0[0]) * tanh_(zc0[1]);
      const float nc1 = creg1 * sigm(zc1[2] + 1.0f) + sigm(zc1[0]) * tanh_(zc1[1]);
      const float s20 = red64(nc0), ss20 = red64(nc0 * nc0);
      const float s21 = red64(nc1), ss21 = red64(nc1 * nc1);
      const float mm0 = s20 * (1.0f / 64.0f), vv0 = ss20 * (1.0f / 64.0f) - mm0 * mm0;
      const float mm1 = s21 * (1.0f / 64.0f), vv1 = ss21 * (1.0f / 64.0f) - mm1 * mm1;
      const float cn0 = (nc0 - mm0) * rsqrtf(vv0 + EPS) * cgam + cbet;
      const float cn1 = (nc1 - mm1) * rsqrtf(vv1 + EPS) * cgam + cbet;
      creg0 = cn0; creg1 = cn1;
      const float h0 = tanh_(cn0) * sigm(zc0[3]);
      const float h1 = tanh_(cn1) * sigm(zc1[3]);
      hh[buf][tm][g][ln] = f2h(h0);
      hh[buf][tm][g + 4][ln] = f2h(h1);
    } else {
      // ---- producer B: stream-stage x(o+2) (steps 4..7, 2 slices each) ----
      if (tm >= 4 && o < 30) {
        #pragma unroll
        for (int k = 0; k < 2; ++k) {
          const int s = (tm - 4) * 2 + k;
          const int tl = (o + 2) * 8 + s;
          const f32x4 v = (slot < 24) ? *(const f32x4*)(obs_p + tl * OBS + slot * 4)
                                      : *(const f32x4*)(act_p + tl * ACTD + (slot - 24) * 4);
          *(uint2*)&xchunk[buf][s][srow][slot * 4] =
              make_uint2(pk2h(v[0], v[1]), pk2h(v[2], v[3]));
        }
      }
    }
    barrier_lds();
  }

  // epilogue: q for octave 31 (steps 248..255) from hh[1]
  if (!cons) {
    const int ra = 2 * (wv - 4);
    #pragma unroll
    for (int s = 0; s < CH; ++s) {
      const float hv0 = (float)__builtin_bit_cast(_Float16, hh[1][s][ra][ln]);
      const float hv1 = (float)__builtin_bit_cast(_Float16, hh[1][s][ra + 1][ln]);
      const float q0 = red64(hv0 * dw);
      const float q1 = red64(hv1 * dw);
      if (ln == 0) {
        out[(size_t)(n0 + ra) * TT + 248 + s] = q0 + bias;
        out[(size_t)(n0 + ra + 1) * TT + 248 + s] = q1 + bias;
      }
    }
  }
}

extern "C" void kernel_launch(void* const* d_in, const int* in_sizes, int n_in,
                              void* d_out, int out_size, void* d_ws, size_t ws_size,
                              hipStream_t stream) {
  const float* obss    = (const float*)d_in[0];
  const float* actions = (const float*)d_in[1];
  const float* Wm      = (const float*)d_in[2];
  const float* gamma   = (const float*)d_in[3];
  const float* beta    = (const float*)d_in[4];
  const float* dWv     = (const float*)d_in[5];
  const float* dbv     = (const float*)d_in[6];
  float* out = (float*)d_out;
  lstm_fused<<<dim3(2048 / RPB), dim3(512), 0, stream>>>(obss, actions, Wm, gamma,
                                                         beta, dWv, dbv, out);
}